// Round 1
// baseline (787.524 us; speedup 1.0000x reference)
//
#include <hip/hip_runtime.h>
#include <math.h>

// DNC MemoryAccess forward. B=8, T=16, N=512, W=64, R=4, NW=1, MODES=3, IFACE=471.
// Persistent cooperative kernel: 128 blocks (16 per batch), link rows + memory rows
// resident in LDS per block; per-batch spin barriers; 2 barriers per timestep.

#define NBATCH 8
#define GPB    16          // blocks per batch
#define NBLK   (NBATCH*GPB)
#define NROW   32          // link/memory rows owned per block
#define NTT    16
#define NSLOT  512
#define WRD    64
#define RH     4
#define NIF    471
#define LSTR   516         // padded LDS row stride for link (floats)
#define MSTR   65          // padded LDS row stride for memory (floats)
#define EPSV   1e-6f

// workspace float offsets (after 4096-byte barrier region)
#define OFF_IFC   0        // [8][16][471]
#define OFF_USAGE 60288    // [8][512]
#define OFF_RW    64384    // [8][4][512]
#define OFF_PREC  80768    // [2][8][512]
#define OFF_EW    88960    // [8][512]
#define OFF_ALLOC 93056    // [8][512]
#define OFF_WCP   97152    // [8][16]
#define OFF_RCP   97280    // [8][16][4]
#define OFF_BWDP  97792    // [8][16][4][512]
#define OFF_RWP   359936   // [8][16][256]
// total floats = 392704  (~1.5 MB)

__device__ __forceinline__ float sigm(float x){ return 1.f/(1.f+expf(-x)); }
__device__ __forceinline__ float softpl(float x){ return x>0.f ? x+log1pf(expf(-x)) : log1pf(expf(x)); }
__device__ __forceinline__ float red8s(float v){ v+=__shfl_xor(v,1,8); v+=__shfl_xor(v,2,8); v+=__shfl_xor(v,4,8); return v; }
__device__ __forceinline__ float red8m(float v){ v*=__shfl_xor(v,1,8); v*=__shfl_xor(v,2,8); v*=__shfl_xor(v,4,8); return v; }
__device__ __forceinline__ float red16s(float v){ v+=__shfl_xor(v,1,16); v+=__shfl_xor(v,2,16); v+=__shfl_xor(v,4,16); v+=__shfl_xor(v,8,16); return v; }
__device__ __forceinline__ float red64s(float v){
  v+=__shfl_xor(v,1); v+=__shfl_xor(v,2); v+=__shfl_xor(v,4);
  v+=__shfl_xor(v,8); v+=__shfl_xor(v,16); v+=__shfl_xor(v,32); return v; }

// per-batch barrier: bar[0]=generation, bar[1]=arrival count (zeroed by hipMemsetAsync)
__device__ __forceinline__ void batch_barrier(unsigned* bar){
  __syncthreads();
  if (threadIdx.x==0){
    unsigned g = __hip_atomic_load(bar, __ATOMIC_RELAXED, __HIP_MEMORY_SCOPE_AGENT);
    __threadfence();
    unsigned old = __hip_atomic_fetch_add(bar+1, 1u, __ATOMIC_ACQ_REL, __HIP_MEMORY_SCOPE_AGENT);
    if (old == (unsigned)(GPB-1)){
      __hip_atomic_store(bar+1, 0u, __ATOMIC_RELAXED, __HIP_MEMORY_SCOPE_AGENT);
      __hip_atomic_fetch_add(bar, 1u, __ATOMIC_RELEASE, __HIP_MEMORY_SCOPE_AGENT);
    } else {
      while (__hip_atomic_load(bar, __ATOMIC_ACQUIRE, __HIP_MEMORY_SCOPE_AGENT) == g)
        __builtin_amdgcn_s_sleep(1);
    }
    __threadfence();
  }
  __syncthreads();
}

__global__ void __launch_bounds__(256)
dnc_kernel(const float* __restrict__ ctrl, const float* __restrict__ wif,
           const float* __restrict__ bif, const float* __restrict__ mem0,
           float* __restrict__ out, float* __restrict__ ws, unsigned* __restrict__ barbase)
{
  const int tid = threadIdx.x;
  const int bid = blockIdx.x;
  const int b   = bid & 7;       // batch -> XCD affinity under %8 mapping (perf only)
  const int g   = bid >> 3;      // group rank within batch, also timestep for init GEMM
  const int n0  = g * NROW;
  unsigned* mybar = barbase + b*32;

  __shared__ __align__(16) float L[NROW*LSTR];     // link rows (persistent)
  __shared__ __align__(16) float Mem[NROW*MSTR];   // memory rows (persistent)
  __shared__ __align__(16) float rwl[RH*NSLOT];    // read_w (prev step), full
  __shared__ __align__(16) float wwl[NSLOT];       // write weights, full
  __shared__ __align__(16) float precl[NSLOT];     // precedence (old), full
  __shared__ __align__(16) float usagel[NSLOT];    // usage (old), full
  __shared__ __align__(16) float ewl[NSLOT];       // write-content exp, full
  __shared__ __align__(16) float allocl[NSLOT];    // allocation, full
  __shared__ __align__(16) float bwdh[RH*NSLOT];   // bwd half-combine scratch (aliases ctrlrow in init)
  __shared__ float prs[480];                       // parsed interface + norms
  __shared__ float ern[RH*NROW];                   // read-content exp, own rows
  __shared__ float fwdl[RH*NROW];                  // fwd, own rows
  __shared__ float rwnl[RH*NROW];                  // new read_w, own rows
  __shared__ float psil[NROW];
  __shared__ float eown[NROW];
  __shared__ float red[16];

  // ---------------- init ----------------
  for (int i=tid; i<NROW*LSTR; i+=256) L[i]=0.f;
  for (int i=tid; i<NROW*WRD; i+=256){
    int r=i>>6, k=i&63;
    Mem[r*MSTR+k] = mem0[(size_t)(b*NSLOT + n0 + r)*WRD + k];
  }
  if (tid < RH*NROW) rwnl[tid]=0.f;
  if (tid < NROW){
    int n=n0+tid;
    ws[OFF_USAGE + b*NSLOT + n]=0.f;
    ws[OFF_PREC  + b*NSLOT + n]=0.f;    // prec buffer p=0
    for (int r=0;r<RH;r++) ws[OFF_RW + b*RH*NSLOT + r*NSLOT + n]=0.f;
  }
  { // interface GEMM: this block computes iface row (b, t=g)
    float* ctrlrow = bwdh; // alias, init-only
    const float* crow = ctrl + (size_t)(b*NTT+g)*1024;
    for (int i=tid;i<1024;i+=256) ctrlrow[i]=crow[i];
    __syncthreads();
    for (int j=tid;j<NIF;j+=256){
      float a0=0.f,a1=0.f,a2=0.f,a3=0.f;
      const float* wp = wif + j;
      for (int c=0;c<1024;c+=4){
        a0 += ctrlrow[c+0]*wp[(size_t)(c+0)*NIF];
        a1 += ctrlrow[c+1]*wp[(size_t)(c+1)*NIF];
        a2 += ctrlrow[c+2]*wp[(size_t)(c+2)*NIF];
        a3 += ctrlrow[c+3]*wp[(size_t)(c+3)*NIF];
      }
      ws[OFF_IFC + (b*NTT+g)*NIF + j] = ((a0+a1)+(a2+a3)) + bif[j];
    }
  }
  batch_barrier(mybar);

  // ---------------- time loop ----------------
  for (int t=0; t<NTT; t++){
    const int p = t & 1;
    __syncthreads();  // protect prs/rwnl reuse from previous iteration

    // ---- parse interface vector ----
    {
      const float* ifc = ws + OFF_IFC + (b*NTT+t)*NIF;
      for (int i=tid;i<NIF;i+=256) prs[i]=ifc[i];
      for (int i=tid;i<NSLOT;i+=256) usagel[i]=ws[OFF_USAGE+b*NSLOT+i];
      __syncthreads();
      if (tid<4) prs[256+tid]=softpl(prs[256+tid]);                       // read strengths
      else if (tid==4) prs[324]=softpl(prs[324]);                         // write strength
      else if (tid>=64 && tid<128) prs[325+(tid-64)]=sigm(prs[325+(tid-64)]); // erase
      else if (tid>=128 && tid<132) prs[453+(tid-128)]=sigm(prs[453+(tid-128)]); // free gates
      else if (tid==132) prs[457]=sigm(prs[457]);                         // alloc gate
      else if (tid==133) prs[458]=sigm(prs[458]);                         // write gate
      else if (tid>=136 && tid<140){                                      // modes softmax
        int r=tid-136;
        float x0=prs[459+r*3],x1=prs[460+r*3],x2=prs[461+r*3];
        float mx=fmaxf(x0,fmaxf(x1,x2));
        float e0=expf(x0-mx),e1=expf(x1-mx),e2=expf(x2-mx),s=e0+e1+e2;
        prs[459+r*3]=e0/s; prs[460+r*3]=e1/s; prs[461+r*3]=e2/s;
      }
      { // key norms: wave0->wk + rk3, waves1..3 -> rk0..2
        int wv=tid>>6, lane=tid&63;
        float v = (wv==0)? prs[260+lane] : prs[(wv-1)*64+lane];
        v = red64s(v*v);
        if (lane==0){ if (wv==0) prs[471]=sqrtf(v); else prs[471+wv]=sqrtf(v); }
        if (wv==0){
          float u=prs[192+lane];
          u=red64s(u*u);
          if (lane==0) prs[475]=sqrtf(u);
        }
      }
      __syncthreads();
    }

    // ---- phase B: write-content dots, sort-free allocation, psi (own rows) ----
    {
      int row=tid>>3, sub=tid&7, n=n0+row;
      float wd=0.f, ms=0.f;
      #pragma unroll
      for (int j=0;j<8;j++){
        int k=sub*8+j; float m=Mem[row*MSTR+k];
        wd += m*prs[260+k]; ms += m*m;
      }
      wd=red8s(wd); ms=red8s(ms);
      float u_n=usagel[n];
      float pr=1.f;
      for (int m=sub;m<NSLOT;m+=8){
        float um=usagel[m];
        if (um<u_n || (um==u_n && m<n)) pr*=um;   // stable-argsort predecessor product
      }
      pr=red8m(pr);
      if (sub==0){
        float e=expf(prs[324]*wd/(prs[471]*sqrtf(ms)+EPSV));
        ws[OFF_EW   +b*NSLOT+n]=e; eown[row]=e;
        ws[OFF_ALLOC+b*NSLOT+n]=(1.f-u_n)*pr;
      }
      if (tid<NROW){
        float pp=1.f;
        #pragma unroll
        for (int r=0;r<RH;r++) pp *= 1.f - prs[453+r]*rwnl[r*NROW+tid];
        psil[tid]=pp;
      }
    }
    __syncthreads();
    if ((tid>>6)==0){ float v=(tid<NROW)?eown[tid]:0.f; v=red64s(v); if (tid==0) ws[OFF_WCP+b*GPB+g]=v; }
    batch_barrier(mybar);   // ---- barrier 1 ----

    // ---- phase C: full ww vector, usage/prec/memory updates, read-content ----
    if (tid<GPB){ float v=ws[OFF_WCP+b*GPB+tid]; v=red16s(v); if (tid==0) red[0]=v; }
    for (int i=tid;i<NSLOT;i+=256){
      ewl[i]   = ws[OFF_EW   +b*NSLOT+i];
      allocl[i]= ws[OFF_ALLOC+b*NSLOT+i];
      precl[i] = ws[OFF_PREC + p*(NBATCH*NSLOT) + b*NSLOT + i];
    }
    for (int i=tid;i<RH*NSLOT;i+=256) rwl[i]=ws[OFF_RW+b*RH*NSLOT+i];
    __syncthreads();
    {
      const float Sw=red[0], agv=prs[457], wgv=prs[458];
      for (int i=tid;i<NSLOT;i+=256) wwl[i]=wgv*(agv*allocl[i]+(1.f-agv)*ewl[i]/Sw);
    }
    __syncthreads();
    {
      float v=wwl[tid]+wwl[tid+256]; v=red64s(v);
      if ((tid&63)==0) red[8+(tid>>6)]=v;
    }
    __syncthreads();
    {
      const float Sww=red[8]+red[9]+red[10]+red[11];
      if (tid<NROW){
        int n=n0+tid; float wn=wwl[n];
        ws[OFF_USAGE+b*NSLOT+n]=(usagel[n]+wn-usagel[n]*wn)*psil[tid];
        ws[OFF_PREC+(p^1)*(NBATCH*NSLOT)+b*NSLOT+n]=(1.f-Sww)*precl[n]+wn;
      }
    }
    { // memory erase/add + read-content dots on updated memory
      int row=tid>>3, sub=tid&7;
      float wn=wwl[n0+row];
      float rd0=0.f,rd1=0.f,rd2=0.f,rd3=0.f,ms=0.f;
      #pragma unroll
      for (int j=0;j<8;j++){
        int k=sub*8+j;
        float m=Mem[row*MSTR+k];
        m = m*(1.f-wn*prs[325+k]) + wn*prs[389+k];
        Mem[row*MSTR+k]=m;
        rd0+=prs[  0+k]*m; rd1+=prs[ 64+k]*m; rd2+=prs[128+k]*m; rd3+=prs[192+k]*m;
        ms+=m*m;
      }
      rd0=red8s(rd0); rd1=red8s(rd1); rd2=red8s(rd2); rd3=red8s(rd3); ms=red8s(ms);
      if (sub==0){
        float mn=sqrtf(ms);
        ern[0*NROW+row]=expf(prs[256]*rd0/(prs[472]*mn+EPSV));
        ern[1*NROW+row]=expf(prs[257]*rd1/(prs[473]*mn+EPSV));
        ern[2*NROW+row]=expf(prs[258]*rd2/(prs[474]*mn+EPSV));
        ern[3*NROW+row]=expf(prs[259]*rd3/(prs[475]*mn+EPSV));
      }
    }
    __syncthreads();
    {
      int wv=tid>>6, lane=tid&63;
      float v=(lane<NROW)?ern[wv*NROW+lane]:0.f; v=red64s(v);
      if (lane==0) ws[OFF_RCP+(b*GPB+g)*RH+wv]=v;
    }
    if (g==0 && t>0){ // finalize read_words for t-1
      float s=0.f;
      for (int gp=0;gp<GPB;gp++) s+=ws[OFF_RWP+(b*GPB+gp)*256+tid];
      out[(size_t)(b*NTT+(t-1))*256+tid]=s;
    }
    __syncthreads();

    // ---- phase D: link update (pass1), fwd (pass2a), bwd partials (pass2b) ----
    for (int i=0;i<16;i++){     // pass1: flat f4 tiles, conflict-free
      int e=tid+256*i, row=e>>7, c4=e&127, mb=4*c4;
      float4 l4=*(float4*)&L[row*LSTR+mb];
      float wn=wwl[n0+row];
      float4 wm=*(float4*)&wwl[mb];
      float4 pm=*(float4*)&precl[mb];
      l4.x=(1.f-wn-wm.x)*l4.x+wn*pm.x;
      l4.y=(1.f-wn-wm.y)*l4.y+wn*pm.y;
      l4.z=(1.f-wn-wm.z)*l4.z+wn*pm.z;
      l4.w=(1.f-wn-wm.w)*l4.w+wn*pm.w;
      int d=(n0+row)-mb;
      if (d>=0 && d<4) ((float*)&l4)[d]=0.f;   // off-diagonal mask
      *(float4*)&L[row*LSTR+mb]=l4;
    }
    __syncthreads();
    { // pass2a: fwd[r][n] = sum_m L[n][m]*rw_old[r][m]; one wave per 8 rows
      int wv=tid>>6, lane=tid&63;
      float4 ra0=*(float4*)&rwl[0*NSLOT+4*lane], rb0=*(float4*)&rwl[0*NSLOT+256+4*lane];
      float4 ra1=*(float4*)&rwl[1*NSLOT+4*lane], rb1=*(float4*)&rwl[1*NSLOT+256+4*lane];
      float4 ra2=*(float4*)&rwl[2*NSLOT+4*lane], rb2=*(float4*)&rwl[2*NSLOT+256+4*lane];
      float4 ra3=*(float4*)&rwl[3*NSLOT+4*lane], rb3=*(float4*)&rwl[3*NSLOT+256+4*lane];
      for (int rr=0;rr<8;rr++){
        int row=wv*8+rr;
        float4 a=*(float4*)&L[row*LSTR+4*lane];
        float4 bq=*(float4*)&L[row*LSTR+256+4*lane];
        float a0=a.x*ra0.x+a.y*ra0.y+a.z*ra0.z+a.w*ra0.w + bq.x*rb0.x+bq.y*rb0.y+bq.z*rb0.z+bq.w*rb0.w;
        float a1=a.x*ra1.x+a.y*ra1.y+a.z*ra1.z+a.w*ra1.w + bq.x*rb1.x+bq.y*rb1.y+bq.z*rb1.z+bq.w*rb1.w;
        float a2=a.x*ra2.x+a.y*ra2.y+a.z*ra2.z+a.w*ra2.w + bq.x*rb2.x+bq.y*rb2.y+bq.z*rb2.z+bq.w*rb2.w;
        float a3=a.x*ra3.x+a.y*ra3.y+a.z*ra3.z+a.w*ra3.w + bq.x*rb3.x+bq.y*rb3.y+bq.z*rb3.z+bq.w*rb3.w;
        a0=red64s(a0); a1=red64s(a1); a2=red64s(a2); a3=red64s(a3);
        if (lane==0){
          fwdl[0*NROW+row]=a0; fwdl[1*NROW+row]=a1;
          fwdl[2*NROW+row]=a2; fwdl[3*NROW+row]=a3;
        }
      }
    }
    { // pass2b: bwd[r][m] partials over own rows; thread owns one f4 column chunk + half the rows
      int c4=tid&127, half=tid>>7, mb=4*c4;
      float ac[4][4];
      #pragma unroll
      for (int r=0;r<4;r++){ ac[r][0]=0.f; ac[r][1]=0.f; ac[r][2]=0.f; ac[r][3]=0.f; }
      for (int rr=0;rr<16;rr++){
        int row=half*16+rr;
        float4 lv=*(float4*)&L[row*LSTR+mb];
        #pragma unroll
        for (int r=0;r<4;r++){
          float w=rwl[r*NSLOT+n0+row];
          ac[r][0]+=lv.x*w; ac[r][1]+=lv.y*w; ac[r][2]+=lv.z*w; ac[r][3]+=lv.w*w;
        }
      }
      if (half==1){
        #pragma unroll
        for (int r=0;r<4;r++) *(float4*)&bwdh[r*NSLOT+mb]=make_float4(ac[r][0],ac[r][1],ac[r][2],ac[r][3]);
      }
      __syncthreads();
      if (half==0){
        #pragma unroll
        for (int r=0;r<4;r++){
          float4 o=*(float4*)&bwdh[r*NSLOT+mb];
          float4 res=make_float4(ac[r][0]+o.x, ac[r][1]+o.y, ac[r][2]+o.z, ac[r][3]+o.w);
          *(float4*)&ws[OFF_BWDP+((size_t)(b*GPB+g)*RH+r)*NSLOT+mb]=res;
        }
      }
    }
    batch_barrier(mybar);   // ---- barrier 2 ----

    // ---- phase E: read weights + read_words partials ----
    if (tid<64){
      int r=tid>>4, gp=tid&15;
      float v=ws[OFF_RCP+(b*GPB+gp)*RH+r];
      v=red16s(v);
      if ((tid&15)==0) red[4+r]=v;
    }
    __syncthreads();
    if (tid < RH*NROW){
      int r=tid>>5, row=tid&31, n=n0+row;
      float s=0.f;
      for (int gp=0;gp<GPB;gp++) s+=ws[OFF_BWDP+((size_t)(b*GPB+gp)*RH+r)*NSLOT+n];
      float rc=ern[r*NROW+row]/red[4+r];
      float rwn=prs[459+r*3]*s + prs[460+r*3]*rc + prs[461+r*3]*fwdl[r*NROW+row];
      ws[OFF_RW+b*RH*NSLOT+r*NSLOT+n]=rwn;
      rwnl[r*NROW+row]=rwn;
    }
    __syncthreads();
    {
      int r=tid>>6, k=tid&63;
      float a=0.f;
      for (int row=0;row<NROW;row++) a+=rwnl[r*NROW+row]*Mem[row*MSTR+k];
      ws[OFF_RWP+(b*GPB+g)*256+tid]=a;
    }
  }

  batch_barrier(mybar);
  if (g==0){ // finalize t=15
    float s=0.f;
    for (int gp=0;gp<GPB;gp++) s+=ws[OFF_RWP+(b*GPB+gp)*256+tid];
    out[(size_t)(b*NTT+15)*256+tid]=s;
  }
}

extern "C" void kernel_launch(void* const* d_in, const int* in_sizes, int n_in,
                              void* d_out, int out_size, void* d_ws, size_t ws_size,
                              hipStream_t stream)
{
  const float* ctrl=(const float*)d_in[0];
  const float* wif =(const float*)d_in[1];
  const float* bif =(const float*)d_in[2];
  const float* mem0=(const float*)d_in[3];
  float* outp=(float*)d_out;
  unsigned* bar=(unsigned*)d_ws;
  float* wsf=(float*)((char*)d_ws+4096);

  hipMemsetAsync(d_ws, 0, 4096, stream);   // zero barrier counters each launch

  void* args[]={(void*)&ctrl,(void*)&wif,(void*)&bif,(void*)&mem0,(void*)&outp,(void*)&wsf,(void*)&bar};
  hipError_t err = hipLaunchCooperativeKernel((void*)dnc_kernel, dim3(NBLK), dim3(256), args, 0, stream);
  if (err != hipSuccess){
    // fallback: plain launch (128 blocks @ ~107KB LDS are trivially co-resident on 256 CUs)
    hipLaunchKernelGGL(dnc_kernel, dim3(NBLK), dim3(256), 0, stream,
                       ctrl, wif, bif, mem0, outp, wsf, bar);
  }
}

// Round 2
// 628.627 us; speedup vs baseline: 1.2528x; 1.2528x over previous
//
#include <hip/hip_runtime.h>
#include <math.h>

// DNC MemoryAccess forward. B=8, T=16, N=512, W=64, R=4, NW=1, MODES=3, IFACE=471.
// Persistent cooperative kernel: 128 blocks (16 per batch). Each block holds 32 rows of
// the link matrix L AND the matching 32 columns (as rows of LT) in LDS, plus its 32
// memory rows. usage/prec/ww/psi are replicated full-vector local computations, so the
// only cross-block exchanges per step are EW/ALLOC (4KB), WCP/RCP sums, rw_new (8KB/batch)
// and read-word partials. Barriers use relaxed spins (no per-poll L2 invalidate).

#define NBATCH 8
#define GPB    16          // blocks per batch
#define NBLK   (NBATCH*GPB)
#define NROW   32          // link rows / LT rows (columns) / memory rows per block
#define NTT    16
#define NSLOT  512
#define WRD    64
#define RH     4
#define NIF    471
#define LSTR   516         // padded LDS row stride for L/LT (floats)
#define MSTR   65          // padded LDS row stride for memory (floats)
#define EPSV   1e-6f

// workspace float offsets (after 4096-byte barrier region)
#define OFF_IFC   0        // [8][16][471]
#define OFF_EW    60288    // [8][512]
#define OFF_ALLOC 64384    // [8][512]
#define OFF_WCP   68480    // [8][16]
#define OFF_RCP   68608    // [8][16][4]
#define OFF_RWN   69120    // [8][4][512]
#define OFF_RWP   85504    // [8][16][256]
// total floats = 118272 (~462 KB)

__device__ __forceinline__ float sigm(float x){ return 1.f/(1.f+expf(-x)); }
__device__ __forceinline__ float softpl(float x){ return x>0.f ? x+log1pf(expf(-x)) : log1pf(expf(x)); }
__device__ __forceinline__ float red8s(float v){ v+=__shfl_xor(v,1,8); v+=__shfl_xor(v,2,8); v+=__shfl_xor(v,4,8); return v; }
__device__ __forceinline__ float red8m(float v){ v*=__shfl_xor(v,1,8); v*=__shfl_xor(v,2,8); v*=__shfl_xor(v,4,8); return v; }
__device__ __forceinline__ float red16s(float v){ v+=__shfl_xor(v,1,16); v+=__shfl_xor(v,2,16); v+=__shfl_xor(v,4,16); v+=__shfl_xor(v,8,16); return v; }
__device__ __forceinline__ float red64s(float v){
  v+=__shfl_xor(v,1); v+=__shfl_xor(v,2); v+=__shfl_xor(v,4);
  v+=__shfl_xor(v,8); v+=__shfl_xor(v,16); v+=__shfl_xor(v,32); return v; }

// per-batch barrier: bar[0]=generation, bar[1]=arrival count (zeroed by hipMemsetAsync).
// Relaxed spin (no buffer_inv per poll); one ACQ_REL RMW per arrival; one acquire fence
// per waiter after observing the flip.
__device__ __forceinline__ void batch_barrier(unsigned* bar, unsigned gen){
  __syncthreads();
  if (threadIdx.x==0){
    unsigned old = __hip_atomic_fetch_add(bar+1, 1u, __ATOMIC_ACQ_REL, __HIP_MEMORY_SCOPE_AGENT);
    if (old == (unsigned)(GPB-1)){
      __hip_atomic_store(bar+1, 0u, __ATOMIC_RELAXED, __HIP_MEMORY_SCOPE_AGENT);
      __hip_atomic_store(bar,  gen, __ATOMIC_RELEASE, __HIP_MEMORY_SCOPE_AGENT);
    } else {
      while (__hip_atomic_load(bar, __ATOMIC_RELAXED, __HIP_MEMORY_SCOPE_AGENT) < gen)
        __builtin_amdgcn_s_sleep(1);
      __builtin_amdgcn_fence(__ATOMIC_ACQUIRE, "agent");
    }
  }
  __syncthreads();
}

__global__ void __launch_bounds__(256)
dnc_kernel(const float* __restrict__ ctrl, const float* __restrict__ wif,
           const float* __restrict__ bif, const float* __restrict__ mem0,
           float* __restrict__ out, float* __restrict__ ws, unsigned* __restrict__ barbase)
{
  const int tid = threadIdx.x;
  const int bid = blockIdx.x;
  const int b   = bid & 7;       // batch (XCD-affine under %8 round-robin; perf only)
  const int g   = bid >> 3;      // group rank within batch
  const int n0  = g * NROW;
  unsigned* mybar = barbase + b*32;
  unsigned gen = 0;

  __shared__ __align__(16) float L  [NROW*LSTR];   // link rows n0..n0+31 (persistent)
  __shared__ __align__(16) float LT [NROW*LSTR];   // link cols n0..n0+31 as rows (persistent)
  __shared__ __align__(16) float Mem[NROW*MSTR];   // memory rows (persistent)
  __shared__ __align__(16) float rwl[RH*NSLOT];    // read_w (prev step), full
  __shared__ __align__(16) float wwl[NSLOT];       // write weights, full (local)
  __shared__ __align__(16) float precl[NSLOT];     // precedence, full (local, persistent)
  __shared__ __align__(16) float usagel[NSLOT];    // usage, full (local, persistent)
  __shared__ __align__(16) float prs[480];         // parsed interface + norms
  __shared__ __align__(16) float aux[560];
  float* ern  = aux;        // [4][32] read-content exp, own rows
  float* fwdl = aux+128;    // [4][32]
  float* bwdl = aux+256;    // [4][32]
  float* rwnl = aux+384;    // [4][32] new read_w own rows
  float* eown = aux+512;    // [32]
  float* red  = aux+544;    // [16]

  // ---------------- init ----------------
  for (int i=tid; i<NROW*LSTR; i+=256){ L[i]=0.f; LT[i]=0.f; }
  for (int i=tid; i<NROW*WRD; i+=256){
    int r=i>>6, k=i&63;
    Mem[r*MSTR+k] = mem0[(size_t)(b*NSLOT + n0 + r)*WRD + k];
  }
  for (int i=tid; i<NSLOT; i+=256){ usagel[i]=0.f; precl[i]=0.f; }
  if (tid < RH*NROW){
    int r=tid>>5, row=tid&31;
    ws[OFF_RWN + b*RH*NSLOT + r*NSLOT + n0 + row] = 0.f;
  }
  { // interface GEMM: this block computes iface row (b, t=g)
    float* ctrlrow = rwl;   // alias, init-only (rwl reloaded each step)
    const float* crow = ctrl + (size_t)(b*NTT+g)*1024;
    for (int i=tid;i<1024;i+=256) ctrlrow[i]=crow[i];
    __syncthreads();
    for (int j=tid;j<NIF;j+=256){
      float a0=0.f,a1=0.f,a2=0.f,a3=0.f;
      const float* wp = wif + j;
      for (int c=0;c<1024;c+=4){
        a0 += ctrlrow[c+0]*wp[(size_t)(c+0)*NIF];
        a1 += ctrlrow[c+1]*wp[(size_t)(c+1)*NIF];
        a2 += ctrlrow[c+2]*wp[(size_t)(c+2)*NIF];
        a3 += ctrlrow[c+3]*wp[(size_t)(c+3)*NIF];
      }
      ws[OFF_IFC + (b*NTT+g)*NIF + j] = ((a0+a1)+(a2+a3)) + bif[j];
    }
  }
  batch_barrier(mybar, ++gen);

  // ---------------- time loop ----------------
  for (int t=0; t<NTT; t++){
    __syncthreads();  // protect prs/aux reuse from previous iteration

    // ---- phase A: parse interface vector ----
    {
      const float* ifc = ws + OFF_IFC + (b*NTT+t)*NIF;
      for (int i=tid;i<NIF;i+=256) prs[i]=ifc[i];
      __syncthreads();
      if (tid<4) prs[256+tid]=softpl(prs[256+tid]);                           // read strengths
      else if (tid==4) prs[324]=softpl(prs[324]);                             // write strength
      else if (tid>=64 && tid<128) prs[325+(tid-64)]=sigm(prs[325+(tid-64)]); // erase
      else if (tid>=128 && tid<132) prs[453+(tid-128)]=sigm(prs[453+(tid-128)]); // free gates
      else if (tid==132) prs[457]=sigm(prs[457]);                             // alloc gate
      else if (tid==133) prs[458]=sigm(prs[458]);                             // write gate
      else if (tid>=136 && tid<140){                                          // modes softmax
        int r=tid-136;
        float x0=prs[459+r*3],x1=prs[460+r*3],x2=prs[461+r*3];
        float mx=fmaxf(x0,fmaxf(x1,x2));
        float e0=expf(x0-mx),e1=expf(x1-mx),e2=expf(x2-mx),s=e0+e1+e2;
        prs[459+r*3]=e0/s; prs[460+r*3]=e1/s; prs[461+r*3]=e2/s;
      }
      { // key norms: wave0 -> wk + rk3, waves1..3 -> rk0..2
        int wv=tid>>6, lane=tid&63;
        float v = (wv==0)? prs[260+lane] : prs[(wv-1)*64+lane];
        v = red64s(v*v);
        if (lane==0){ prs[471+wv]=sqrtf(v); }     // 471=wk, 472..474=rk0..2
        if (wv==0){
          float u=prs[192+lane];
          u=red64s(u*u);
          if (lane==0) prs[475]=sqrtf(u);         // rk3
        }
      }
      __syncthreads();
    }

    // ---- phase B: write-content dots + sort-free allocation (own rows) ----
    {
      int row=tid>>3, sub=tid&7, n=n0+row;
      float wd=0.f, ms=0.f;
      #pragma unroll
      for (int j=0;j<8;j++){
        int k=sub*8+j; float m=Mem[row*MSTR+k];
        wd += m*prs[260+k]; ms += m*m;
      }
      wd=red8s(wd); ms=red8s(ms);
      float u_n=usagel[n];
      float pr=1.f;
      for (int m=sub;m<NSLOT;m+=8){
        float um=usagel[m];
        if (um<u_n || (um==u_n && m<n)) pr*=um;   // stable-argsort predecessor product
      }
      pr=red8m(pr);
      if (sub==0){
        float e=expf(prs[324]*wd/(prs[471]*sqrtf(ms)+EPSV));
        ws[OFF_EW   +b*NSLOT+n]=e; eown[row]=e;
        ws[OFF_ALLOC+b*NSLOT+n]=(1.f-u_n)*pr;
      }
    }
    __syncthreads();
    if ((tid>>6)==0){ float v=(tid<NROW)?eown[tid]:0.f; v=red64s(v); if (tid==0) ws[OFF_WCP+b*GPB+g]=v; }
    batch_barrier(mybar, ++gen);   // ---- barrier 1 ----

    // ---- C1: gather Sw, reload rw(prev), finalize out[t-1] ----
    if (tid<GPB){ float v=ws[OFF_WCP+b*GPB+tid]; v=red16s(v); if (tid==0) red[0]=v; }
    for (int i=tid;i<RH*NSLOT;i+=256) rwl[i]=ws[OFF_RWN+b*RH*NSLOT+i];
    if (g==0 && t>0){
      float s=0.f;
      for (int gp=0;gp<GPB;gp++) s+=ws[OFF_RWP+(b*GPB+gp)*256+tid];
      out[(size_t)(b*NTT+(t-1))*256+tid]=s;
    }
    __syncthreads();

    // ---- C2: full write weights (local) ----
    {
      const float Sw=red[0], agv=prs[457], wgv=prs[458];
      for (int i=tid;i<NSLOT;i+=256){
        float ew=ws[OFF_EW+b*NSLOT+i], al=ws[OFF_ALLOC+b*NSLOT+i];
        wwl[i]=wgv*(agv*al+(1.f-agv)*ew/Sw);
      }
    }
    __syncthreads();

    // ---- C3: Sww partials, L & LT updates (prec old), mem update + read-content ----
    { float v=wwl[tid]+wwl[tid+256]; v=red64s(v); if ((tid&63)==0) red[8+(tid>>6)]=v; }
    for (int i=0;i<16;i++){   // L[n own][m]: (1-w_n-w_m)L + w_n p_m
      int e=tid+256*i, row=e>>7, mb=(e&127)*4;
      float4 l4=*(float4*)&L[row*LSTR+mb];
      float wn=wwl[n0+row];
      float4 wm=*(float4*)&wwl[mb];
      float4 pm=*(float4*)&precl[mb];
      l4.x=(1.f-wn-wm.x)*l4.x+wn*pm.x;
      l4.y=(1.f-wn-wm.y)*l4.y+wn*pm.y;
      l4.z=(1.f-wn-wm.z)*l4.z+wn*pm.z;
      l4.w=(1.f-wn-wm.w)*l4.w+wn*pm.w;
      int d=(n0+row)-mb;
      if (d>=0 && d<4) ((float*)&l4)[d]=0.f;
      *(float4*)&L[row*LSTR+mb]=l4;
    }
    for (int i=0;i<16;i++){   // LT[m own][n]: (1-w_m-w_n)LT + w_n p_m
      int e=tid+256*i, row=e>>7, mb=(e&127)*4;
      float4 l4=*(float4*)&LT[row*LSTR+mb];
      float wm_=wwl[n0+row];        // w_m (own column index)
      float pm_=precl[n0+row];      // p_m (old)
      float4 wn4=*(float4*)&wwl[mb];
      l4.x=(1.f-wm_-wn4.x)*l4.x+wn4.x*pm_;
      l4.y=(1.f-wm_-wn4.y)*l4.y+wn4.y*pm_;
      l4.z=(1.f-wm_-wn4.z)*l4.z+wn4.z*pm_;
      l4.w=(1.f-wm_-wn4.w)*l4.w+wn4.w*pm_;
      int d=(n0+row)-mb;
      if (d>=0 && d<4) ((float*)&l4)[d]=0.f;
      *(float4*)&LT[row*LSTR+mb]=l4;
    }
    { // memory erase/add + read-content dots on updated memory (own rows)
      int row=tid>>3, sub=tid&7;
      float wn=wwl[n0+row];
      float rd0=0.f,rd1=0.f,rd2=0.f,rd3=0.f,ms=0.f;
      #pragma unroll
      for (int j=0;j<8;j++){
        int k=sub*8+j;
        float m=Mem[row*MSTR+k];
        m = m*(1.f-wn*prs[325+k]) + wn*prs[389+k];
        Mem[row*MSTR+k]=m;
        rd0+=prs[  0+k]*m; rd1+=prs[ 64+k]*m; rd2+=prs[128+k]*m; rd3+=prs[192+k]*m;
        ms+=m*m;
      }
      rd0=red8s(rd0); rd1=red8s(rd1); rd2=red8s(rd2); rd3=red8s(rd3); ms=red8s(ms);
      if (sub==0){
        float mn=sqrtf(ms);
        ern[0*NROW+row]=expf(prs[256]*rd0/(prs[472]*mn+EPSV));
        ern[1*NROW+row]=expf(prs[257]*rd1/(prs[473]*mn+EPSV));
        ern[2*NROW+row]=expf(prs[258]*rd2/(prs[474]*mn+EPSV));
        ern[3*NROW+row]=expf(prs[259]*rd3/(prs[475]*mn+EPSV));
      }
    }
    __syncthreads();

    // ---- C4: usage/prec full update (local), fwd+bwd (own rows), RCP partials ----
    {
      const float Sww=red[8]+red[9]+red[10]+red[11];
      for (int i=tid;i<NSLOT;i+=256){
        float wn=wwl[i];
        float psi=(1.f-prs[453]*rwl[i])
                 *(1.f-prs[454]*rwl[NSLOT+i])
                 *(1.f-prs[455]*rwl[2*NSLOT+i])
                 *(1.f-prs[456]*rwl[3*NSLOT+i]);
        usagel[i]=(usagel[i]+wn-usagel[i]*wn)*psi;
        precl[i]=(1.f-Sww)*precl[i]+wn;
      }
    }
    { // fwd[r][n own] = L[n]·rw[r];  bwd[r][m own] = LT[m]·rw[r]
      int wv=tid>>6, lane=tid&63;
      float4 ra0=*(float4*)&rwl[0*NSLOT+4*lane], rb0=*(float4*)&rwl[0*NSLOT+256+4*lane];
      float4 ra1=*(float4*)&rwl[1*NSLOT+4*lane], rb1=*(float4*)&rwl[1*NSLOT+256+4*lane];
      float4 ra2=*(float4*)&rwl[2*NSLOT+4*lane], rb2=*(float4*)&rwl[2*NSLOT+256+4*lane];
      float4 ra3=*(float4*)&rwl[3*NSLOT+4*lane], rb3=*(float4*)&rwl[3*NSLOT+256+4*lane];
      for (int rr=0;rr<8;rr++){
        int row=wv*8+rr;
        float4 a=*(float4*)&L[row*LSTR+4*lane];
        float4 bq=*(float4*)&L[row*LSTR+256+4*lane];
        float f0=a.x*ra0.x+a.y*ra0.y+a.z*ra0.z+a.w*ra0.w + bq.x*rb0.x+bq.y*rb0.y+bq.z*rb0.z+bq.w*rb0.w;
        float f1=a.x*ra1.x+a.y*ra1.y+a.z*ra1.z+a.w*ra1.w + bq.x*rb1.x+bq.y*rb1.y+bq.z*rb1.z+bq.w*rb1.w;
        float f2=a.x*ra2.x+a.y*ra2.y+a.z*ra2.z+a.w*ra2.w + bq.x*rb2.x+bq.y*rb2.y+bq.z*rb2.z+bq.w*rb2.w;
        float f3=a.x*ra3.x+a.y*ra3.y+a.z*ra3.z+a.w*ra3.w + bq.x*rb3.x+bq.y*rb3.y+bq.z*rb3.z+bq.w*rb3.w;
        float4 c=*(float4*)&LT[row*LSTR+4*lane];
        float4 dq=*(float4*)&LT[row*LSTR+256+4*lane];
        float b0=c.x*ra0.x+c.y*ra0.y+c.z*ra0.z+c.w*ra0.w + dq.x*rb0.x+dq.y*rb0.y+dq.z*rb0.z+dq.w*rb0.w;
        float b1=c.x*ra1.x+c.y*ra1.y+c.z*ra1.z+c.w*ra1.w + dq.x*rb1.x+dq.y*rb1.y+dq.z*rb1.z+dq.w*rb1.w;
        float b2=c.x*ra2.x+c.y*ra2.y+c.z*ra2.z+c.w*ra2.w + dq.x*rb2.x+dq.y*rb2.y+dq.z*rb2.z+dq.w*rb2.w;
        float b3=c.x*ra3.x+c.y*ra3.y+c.z*ra3.z+c.w*ra3.w + dq.x*rb3.x+dq.y*rb3.y+dq.z*rb3.z+dq.w*rb3.w;
        f0=red64s(f0); f1=red64s(f1); f2=red64s(f2); f3=red64s(f3);
        b0=red64s(b0); b1=red64s(b1); b2=red64s(b2); b3=red64s(b3);
        if (lane==0){
          fwdl[0*NROW+row]=f0; fwdl[1*NROW+row]=f1; fwdl[2*NROW+row]=f2; fwdl[3*NROW+row]=f3;
          bwdl[0*NROW+row]=b0; bwdl[1*NROW+row]=b1; bwdl[2*NROW+row]=b2; bwdl[3*NROW+row]=b3;
        }
      }
    }
    { // RCP partials (read-content row sums, own rows)
      int wv=tid>>6, lane=tid&63;
      float v=(lane<NROW)?ern[wv*NROW+lane]:0.f; v=red64s(v);
      if (lane==0) ws[OFF_RCP+(b*GPB+g)*RH+wv]=v;
    }
    batch_barrier(mybar, ++gen);   // ---- barrier 2 ----

    // ---- phase E: read weights (own rows) + read_words partials ----
    if (tid<64){
      int r=tid>>4, gp=tid&15;
      float v=ws[OFF_RCP+(b*GPB+gp)*RH+r];
      v=red16s(v);
      if ((tid&15)==0) red[4+r]=v;
    }
    __syncthreads();
    if (tid < RH*NROW){
      int r=tid>>5, row=tid&31, n=n0+row;
      float rc=ern[r*NROW+row]/red[4+r];
      float rwn=prs[459+r*3]*bwdl[r*NROW+row] + prs[460+r*3]*rc + prs[461+r*3]*fwdl[r*NROW+row];
      ws[OFF_RWN+b*RH*NSLOT+r*NSLOT+n]=rwn;
      rwnl[r*NROW+row]=rwn;
    }
    __syncthreads();
    {
      int r=tid>>6, k=tid&63;
      float a=0.f;
      for (int row=0;row<NROW;row++) a+=rwnl[r*NROW+row]*Mem[row*MSTR+k];
      ws[OFF_RWP+(b*GPB+g)*256+tid]=a;
    }
  }

  batch_barrier(mybar, ++gen);
  if (g==0){ // finalize t=15
    float s=0.f;
    for (int gp=0;gp<GPB;gp++) s+=ws[OFF_RWP+(b*GPB+gp)*256+tid];
    out[(size_t)(b*NTT+15)*256+tid]=s;
  }
}

extern "C" void kernel_launch(void* const* d_in, const int* in_sizes, int n_in,
                              void* d_out, int out_size, void* d_ws, size_t ws_size,
                              hipStream_t stream)
{
  const float* ctrl=(const float*)d_in[0];
  const float* wif =(const float*)d_in[1];
  const float* bif =(const float*)d_in[2];
  const float* mem0=(const float*)d_in[3];
  float* outp=(float*)d_out;
  unsigned* bar=(unsigned*)d_ws;
  float* wsf=(float*)((char*)d_ws+4096);

  hipMemsetAsync(d_ws, 0, 4096, stream);   // zero barrier counters each launch

  void* args[]={(void*)&ctrl,(void*)&wif,(void*)&bif,(void*)&mem0,(void*)&outp,(void*)&wsf,(void*)&bar};
  hipError_t err = hipLaunchCooperativeKernel((void*)dnc_kernel, dim3(NBLK), dim3(256), args, 0, stream);
  if (err != hipSuccess){
    // fallback: plain launch (128 blocks @ 1 block/CU are trivially co-resident on 256 CUs)
    hipLaunchKernelGGL(dnc_kernel, dim3(NBLK), dim3(256), 0, stream,
                       ctrl, wif, bif, mem0, outp, wsf, bar);
  }
}

// Round 3
// 537.810 us; speedup vs baseline: 1.4643x; 1.1689x over previous
//
#include <hip/hip_runtime.h>
#include <math.h>

// DNC MemoryAccess forward. B=8, T=16, N=512, W=64, R=4, NW=1, MODES=3, IFACE=471.
// Persistent kernel: 128 blocks (16/batch). L + LT + Mem shards in LDS; usage/prec/ww
// replicated per block. ONE relaxed flag-barrier per step; all cross-block data moves
// via relaxed agent-scope atomics (per-access coherence, no cache-wide fences).
// Pipelining: wc-dots & alloc for step t+1 are published during step t; read_words are
// a 2-deep partials pipeline.

#define NBATCH 8
#define GPB    16
#define NBLK   (NBATCH*GPB)
#define NROW   32
#define NTT    16
#define NSLOT  512
#define WRD    64
#define RH     4
#define NIF    471
#define LSTR   520          // L/LT row stride (floats): 2-way-max bank aliasing
#define MSTR   65
#define EPSV   1e-6f

// per-parity per-batch float offsets in exchange region
#define B_ALO  0            // [512] allocation
#define B_WDT  512          // [512] write-content raw dots
#define B_MNR  1024         // [512] memory row norms
#define B_ER   1536         // [4][512] read-content exp
#define B_SEP  3584         // [16][4] partial sums of ER
#define B_NN   3648         // [4][512] m0*bwd+m2*fwd
#define B_RWP  5696         // [16][256] read-word partials
#define BATF   9792
#define IFCF   (NBATCH*NTT*NIF)     // 60288 floats of iface
#define PARF   (NBATCH*BATF)

__device__ __forceinline__ float sigm(float x){ return 1.f/(1.f+expf(-x)); }
__device__ __forceinline__ float softpl(float x){ return x>0.f ? x+log1pf(expf(-x)) : log1pf(expf(x)); }
__device__ __forceinline__ float red8s(float v){ v+=__shfl_xor(v,1,8); v+=__shfl_xor(v,2,8); v+=__shfl_xor(v,4,8); return v; }
__device__ __forceinline__ float red8m(float v){ v*=__shfl_xor(v,1,8); v*=__shfl_xor(v,2,8); v*=__shfl_xor(v,4,8); return v; }
__device__ __forceinline__ float red64s(float v){
  v+=__shfl_xor(v,1); v+=__shfl_xor(v,2); v+=__shfl_xor(v,4);
  v+=__shfl_xor(v,8); v+=__shfl_xor(v,16); v+=__shfl_xor(v,32); return v; }

__device__ __forceinline__ void stg(float* p, float v){
  __hip_atomic_store(p, v, __ATOMIC_RELAXED, __HIP_MEMORY_SCOPE_AGENT);
}
__device__ __forceinline__ float ldc(const float* p){
  return __hip_atomic_load(p, __ATOMIC_RELAXED, __HIP_MEMORY_SCOPE_AGENT);
}

// light barrier: per-block generation flags, no fences. Each thread has already
// issued its publishes; waitcnt drains them to the coherence point, then flag.
__device__ __forceinline__ void lbar(unsigned* flg, int b, int g, unsigned gen, int tid){
  asm volatile("s_waitcnt vmcnt(0)" ::: "memory");
  __syncthreads();
  if (tid==0) __hip_atomic_store(flg+b*GPB+g, gen, __ATOMIC_RELAXED, __HIP_MEMORY_SCOPE_AGENT);
  if (tid<GPB){
    while (__hip_atomic_load(flg+b*GPB+tid, __ATOMIC_RELAXED, __HIP_MEMORY_SCOPE_AGENT) < gen)
      __builtin_amdgcn_s_sleep(1);
  }
  __syncthreads();
  asm volatile("" ::: "memory");
}

__global__ void __launch_bounds__(256)
dnc_kernel(const float* __restrict__ ctrl, const float* __restrict__ wif,
           const float* __restrict__ bif, const float* __restrict__ mem0,
           float* __restrict__ out, float* __restrict__ ws, unsigned* __restrict__ flg)
{
  const int tid = threadIdx.x;
  const int bid = blockIdx.x;
  const int b   = bid & 7;
  const int g   = bid >> 3;
  const int n0  = g * NROW;

  __shared__ __align__(16) float L  [NROW*LSTR];
  __shared__ __align__(16) float LT [NROW*LSTR];
  __shared__ __align__(16) float Mem[NROW*MSTR];
  __shared__ __align__(16) float rwl[RH*NSLOT];
  __shared__ __align__(16) float wwl[NSLOT];
  __shared__ __align__(16) float usagel[NSLOT];
  __shared__ __align__(16) float precl[NSLOT];
  __shared__ __align__(16) float prs[480];
  __shared__ __align__(16) float aux[520];
  float* ern    = aux;        // [4][32]
  float* fwdb   = aux+128;    // [4][32]
  float* bwdb   = aux+256;    // [4][32]
  float* mnormo = aux+384;    // [32]
  float* modesA = aux+416;    // [12]
  float* red    = aux+432;    // [16]
  float* wkst   = aux+448;    // [64]

  // ---------------- init ----------------
  for (int i=tid; i<NROW*LSTR; i+=256){ L[i]=0.f; LT[i]=0.f; }
  for (int i=tid; i<NROW*WRD; i+=256){
    int r=i>>6, k=i&63;
    Mem[r*MSTR+k] = mem0[(size_t)(b*NSLOT + n0 + r)*WRD + k];
  }
  for (int i=tid; i<NSLOT; i+=256){ usagel[i]=0.f; precl[i]=0.f; }
  { // iface GEMM: this block computes iface row (b, t=g); stage ctrl row in rwl
    float* ctrlrow = rwl;
    const float* crow = ctrl + (size_t)(b*NTT+g)*1024;
    for (int i=tid;i<1024;i+=256) ctrlrow[i]=crow[i];
    __syncthreads();
    for (int j=tid;j<NIF;j+=256){
      float a0=0.f,a1=0.f,a2=0.f,a3=0.f;
      const float* wp = wif + j;
      for (int c=0;c<1024;c+=4){
        a0 += ctrlrow[c+0]*wp[(size_t)(c+0)*NIF];
        a1 += ctrlrow[c+1]*wp[(size_t)(c+1)*NIF];
        a2 += ctrlrow[c+2]*wp[(size_t)(c+2)*NIF];
        a3 += ctrlrow[c+3]*wp[(size_t)(c+3)*NIF];
      }
      ws[(size_t)(b*NTT+g)*NIF + j] = ((a0+a1)+(a2+a3)) + bif[j];
    }
  }
  __syncthreads();
  for (int i=tid;i<RH*NSLOT;i+=256) rwl[i]=0.f;

  // heavy barrier (gen 1): makes plain-stored iface + everything visible once
  __syncthreads();
  __builtin_amdgcn_fence(__ATOMIC_RELEASE, "agent");
  if (tid==0) __hip_atomic_store(flg+b*GPB+g, 1u, __ATOMIC_RELAXED, __HIP_MEMORY_SCOPE_AGENT);
  if (tid<GPB){
    while (__hip_atomic_load(flg+b*GPB+tid, __ATOMIC_RELAXED, __HIP_MEMORY_SCOPE_AGENT) < 1u)
      __builtin_amdgcn_s_sleep(1);
  }
  __syncthreads();
  __builtin_amdgcn_fence(__ATOMIC_ACQUIRE, "agent");

  // init publish (for step 0) into parity buffer 0
  {
    float* qb = ws + IFCF + 0*PARF + b*BATF;
    if (tid<64) wkst[tid] = ws[(size_t)(b*NTT+0)*NIF + 260 + tid];  // wk_0 (plain, post-fence)
    __syncthreads();
    { // wc dots + mnorm on mem0 shard
      int row=tid>>3, sub=tid&7;
      float wd=0.f, ms=0.f;
      #pragma unroll
      for (int j=0;j<8;j++){
        int k=sub*8+j; float m=Mem[row*MSTR+k];
        wd += m*wkst[k]; ms += m*m;
      }
      wd=red8s(wd); ms=red8s(ms);
      if (sub==0){ stg(qb+B_WDT+n0+row, wd); stg(qb+B_MNR+n0+row, sqrtf(ms)); }
    }
    { // alloc_0 shard from zero usage (generic code -> [1,0,0,...])
      int row=tid>>3, sub=tid&7, n=n0+row;
      float u_n=usagel[n], pr=1.f;
      for (int m=sub;m<NSLOT;m+=8){
        float um=usagel[m];
        if (um<u_n || (um==u_n && m<n)) pr*=um;
      }
      pr=red8m(pr);
      if (sub==0) stg(qb+B_ALO+n, (1.f-u_n)*pr);
    }
  }
  lbar(flg, b, g, 2u, tid);

  // ---------------- time loop (t==NTT is the drain pseudo-step) ----------------
  for (int t=0; t<=NTT; t++){
    const float* pb = ws + IFCF + (t&1)*PARF + b*BATF;        // read buffer
    float*       qb = ws + IFCF + ((t+1)&1)*PARF + b*BATF;    // publish buffer

    // ---- phase 1: assemble rw_{t-1}, read-word partials, drain out[t-2] ----
    if (t>0){
      if (tid<64){
        int gp=tid>>2, r=tid&3;
        float v=ldc(pb+B_SEP+gp*4+r);
        v+=__shfl_xor(v,4); v+=__shfl_xor(v,8); v+=__shfl_xor(v,16); v+=__shfl_xor(v,32);
        if (tid<4) red[tid]=v;   // Se[r]
      }
      __syncthreads();
      {
        float is[4]={1.f/red[0],1.f/red[1],1.f/red[2],1.f/red[3]};
        float m1[4]={modesA[1],modesA[4],modesA[7],modesA[10]};
        #pragma unroll
        for (int i=0;i<8;i++){
          int idx=tid+256*i; int r=idx>>9;
          float e=ldc(pb+B_ER+idx), nn=ldc(pb+B_NN+idx);
          rwl[idx] = nn + m1[r]*e*is[r];
        }
      }
      __syncthreads();
      { // read-word partials for t-1 (Mem shard still = Mem_{t-1})
        int r=tid>>6, k=tid&63;
        float a=0.f;
        #pragma unroll
        for (int row=0;row<NROW;row++) a += rwl[r*NSLOT+n0+row]*Mem[row*MSTR+k];
        stg(qb+B_RWP+g*256+tid, a);
      }
      if (g==0 && t>=2){
        float s=0.f;
        for (int gp=0;gp<GPB;gp++) s+=ldc(pb+B_RWP+gp*256+tid);
        out[(size_t)(b*NTT+(t-2))*256+tid]=s;
      }
    }
    if (t==NTT) break;   // drain step: only phase 1 + final barrier below

    __syncthreads();

    // ---- phase 2a: parse iface_t ----
    {
      const float* ifc = ws + (size_t)(b*NTT+t)*NIF;
      for (int i=tid;i<NIF;i+=256) prs[i]=ifc[i];
      __syncthreads();
      if (tid<4) prs[256+tid]=softpl(prs[256+tid]);
      else if (tid==4) prs[324]=softpl(prs[324]);
      else if (tid>=64 && tid<128) prs[325+(tid-64)]=sigm(prs[325+(tid-64)]);
      else if (tid>=128 && tid<132) prs[453+(tid-128)]=sigm(prs[453+(tid-128)]);
      else if (tid==132) prs[457]=sigm(prs[457]);
      else if (tid==133) prs[458]=sigm(prs[458]);
      else if (tid>=136 && tid<140){
        int r=tid-136;
        float x0=prs[459+r*3],x1=prs[460+r*3],x2=prs[461+r*3];
        float mx=fmaxf(x0,fmaxf(x1,x2));
        float e0=expf(x0-mx),e1=expf(x1-mx),e2=expf(x2-mx),s=e0+e1+e2;
        prs[459+r*3]=e0/s; prs[460+r*3]=e1/s; prs[461+r*3]=e2/s;
        modesA[r*3+0]=e0/s; modesA[r*3+1]=e1/s; modesA[r*3+2]=e2/s;
      }
      {
        int wv=tid>>6, lane=tid&63;
        float v = (wv==0)? prs[260+lane] : prs[(wv-1)*64+lane];
        v = red64s(v*v);
        if (lane==0) prs[471+wv]=sqrtf(v);
        if (wv==0){
          float u=prs[192+lane];
          u=red64s(u*u);
          if (lane==0) prs[475]=sqrtf(u);
        }
      }
      __syncthreads();
    }

    // ---- phase 2b: write-content exp (into wwl), Sw, ww, Sww ----
    {
      float wsv=prs[324], wkn=prs[471];
      for (int i=tid;i<NSLOT;i+=256){
        float wd=ldc(pb+B_WDT+i), mn=ldc(pb+B_MNR+i);
        wwl[i]=expf(wsv*wd/(wkn*mn+EPSV));
      }
    }
    __syncthreads();
    { float v=wwl[tid]+wwl[tid+256]; v=red64s(v); if ((tid&63)==0) red[4+(tid>>6)]=v; }
    __syncthreads();
    {
      const float Sw=red[4]+red[5]+red[6]+red[7];
      float agv=prs[457], wgv=prs[458], isw=1.f/Sw;
      for (int i=tid;i<NSLOT;i+=256){
        float al=ldc(pb+B_ALO+i);
        wwl[i]=wgv*(agv*al+(1.f-agv)*wwl[i]*isw);
      }
    }
    __syncthreads();

    // ---- S1: Sww partials, usage update, L & LT updates (prec old) ----
    { float v=wwl[tid]+wwl[tid+256]; v=red64s(v); if ((tid&63)==0) red[8+(tid>>6)]=v; }
    for (int i=tid;i<NSLOT;i+=256){
      float wn=wwl[i];
      float psi=(1.f-prs[453]*rwl[i])*(1.f-prs[454]*rwl[NSLOT+i])
               *(1.f-prs[455]*rwl[2*NSLOT+i])*(1.f-prs[456]*rwl[3*NSLOT+i]);
      usagel[i]=(usagel[i]+wn-usagel[i]*wn)*psi;
    }
    for (int i=0;i<16;i++){   // L[n own][m]
      int e=tid+256*i, row=e>>7, mb=(e&127)*4;
      float4 l4=*(float4*)&L[row*LSTR+mb];
      float wn=wwl[n0+row];
      float4 wm=*(float4*)&wwl[mb];
      float4 pm=*(float4*)&precl[mb];
      l4.x=(1.f-wn-wm.x)*l4.x+wn*pm.x;
      l4.y=(1.f-wn-wm.y)*l4.y+wn*pm.y;
      l4.z=(1.f-wn-wm.z)*l4.z+wn*pm.z;
      l4.w=(1.f-wn-wm.w)*l4.w+wn*pm.w;
      int d=(n0+row)-mb;
      if (d>=0 && d<4) ((float*)&l4)[d]=0.f;
      *(float4*)&L[row*LSTR+mb]=l4;
    }
    for (int i=0;i<16;i++){   // LT[m own][n]
      int e=tid+256*i, row=e>>7, mb=(e&127)*4;
      float4 l4=*(float4*)&LT[row*LSTR+mb];
      float wm_=wwl[n0+row];
      float pm_=precl[n0+row];
      float4 wn4=*(float4*)&wwl[mb];
      l4.x=(1.f-wm_-wn4.x)*l4.x+wn4.x*pm_;
      l4.y=(1.f-wm_-wn4.y)*l4.y+wn4.y*pm_;
      l4.z=(1.f-wm_-wn4.z)*l4.z+wn4.z*pm_;
      l4.w=(1.f-wm_-wn4.w)*l4.w+wn4.w*pm_;
      int d=(n0+row)-mb;
      if (d>=0 && d<4) ((float*)&l4)[d]=0.f;
      *(float4*)&LT[row*LSTR+mb]=l4;
    }
    __syncthreads();

    // ---- S2: prec update, wk_{t+1} stage, Mem update + read-content dots ----
    {
      const float Sww=red[8]+red[9]+red[10]+red[11];
      for (int i=tid;i<NSLOT;i+=256) precl[i]=(1.f-Sww)*precl[i]+wwl[i];
    }
    if (t<NTT-1 && tid<64) wkst[tid] = ws[(size_t)(b*NTT+t+1)*NIF + 260 + tid];
    {
      int row=tid>>3, sub=tid&7;
      float wn=wwl[n0+row];
      float rd0=0.f,rd1=0.f,rd2=0.f,rd3=0.f,ms=0.f;
      #pragma unroll
      for (int j=0;j<8;j++){
        int k=sub*8+j;
        float m=Mem[row*MSTR+k];
        m = m*(1.f-wn*prs[325+k]) + wn*prs[389+k];
        Mem[row*MSTR+k]=m;
        rd0+=prs[  0+k]*m; rd1+=prs[ 64+k]*m; rd2+=prs[128+k]*m; rd3+=prs[192+k]*m;
        ms+=m*m;
      }
      rd0=red8s(rd0); rd1=red8s(rd1); rd2=red8s(rd2); rd3=red8s(rd3); ms=red8s(ms);
      if (sub==0){
        float mn=sqrtf(ms);
        ern[0*NROW+row]=expf(prs[256]*rd0/(prs[472]*mn+EPSV));
        ern[1*NROW+row]=expf(prs[257]*rd1/(prs[473]*mn+EPSV));
        ern[2*NROW+row]=expf(prs[258]*rd2/(prs[474]*mn+EPSV));
        ern[3*NROW+row]=expf(prs[259]*rd3/(prs[475]*mn+EPSV));
        mnormo[row]=mn;
      }
    }

    // ---- S3: fwd/bwd shards: fwd=L_new·rw, bwd=LT_new·rw (k-sliced, red8) ----
    {
      int row=tid>>3, sub=tid&7;
      const float* Lr = &L[row*LSTR];
      const float* Tr = &LT[row*LSTR];
      float fa0=0.f,fa1=0.f,fa2=0.f,fa3=0.f, ba0=0.f,ba1=0.f,ba2=0.f,ba3=0.f;
      #pragma unroll 4
      for (int jj=0;jj<16;jj++){
        int c4=(sub+8*jj)*4;
        float4 l4=*(const float4*)&Lr[c4];
        float4 t4=*(const float4*)&Tr[c4];
        float4 r0=*(const float4*)&rwl[0*NSLOT+c4];
        float4 r1=*(const float4*)&rwl[1*NSLOT+c4];
        float4 r2=*(const float4*)&rwl[2*NSLOT+c4];
        float4 r3=*(const float4*)&rwl[3*NSLOT+c4];
        fa0+=l4.x*r0.x+l4.y*r0.y+l4.z*r0.z+l4.w*r0.w;
        fa1+=l4.x*r1.x+l4.y*r1.y+l4.z*r1.z+l4.w*r1.w;
        fa2+=l4.x*r2.x+l4.y*r2.y+l4.z*r2.z+l4.w*r2.w;
        fa3+=l4.x*r3.x+l4.y*r3.y+l4.z*r3.z+l4.w*r3.w;
        ba0+=t4.x*r0.x+t4.y*r0.y+t4.z*r0.z+t4.w*r0.w;
        ba1+=t4.x*r1.x+t4.y*r1.y+t4.z*r1.z+t4.w*r1.w;
        ba2+=t4.x*r2.x+t4.y*r2.y+t4.z*r2.z+t4.w*r2.w;
        ba3+=t4.x*r3.x+t4.y*r3.y+t4.z*r3.z+t4.w*r3.w;
      }
      fa0=red8s(fa0); fa1=red8s(fa1); fa2=red8s(fa2); fa3=red8s(fa3);
      ba0=red8s(ba0); ba1=red8s(ba1); ba2=red8s(ba2); ba3=red8s(ba3);
      if (sub==0){
        fwdb[0*NROW+row]=fa0; fwdb[1*NROW+row]=fa1; fwdb[2*NROW+row]=fa2; fwdb[3*NROW+row]=fa3;
        bwdb[0*NROW+row]=ba0; bwdb[1*NROW+row]=ba1; bwdb[2*NROW+row]=ba2; bwdb[3*NROW+row]=ba3;
      }
    }
    __syncthreads();

    // ---- S4: publishes (NN/ER/SEP, MNR, alloc_{t+1}, wc-dots_{t+1}) ----
    if (tid<128){
      int r=tid>>5, row=tid&31;
      float e=ern[r*NROW+row];
      stg(qb+B_NN+r*NSLOT+n0+row, modesA[r*3+0]*bwdb[r*NROW+row] + modesA[r*3+2]*fwdb[r*NROW+row]);
      stg(qb+B_ER+r*NSLOT+n0+row, e);
      float v=e;
      v+=__shfl_xor(v,1,32); v+=__shfl_xor(v,2,32); v+=__shfl_xor(v,4,32);
      v+=__shfl_xor(v,8,32); v+=__shfl_xor(v,16,32);
      if (row==0) stg(qb+B_SEP+g*4+r, v);
    }
    if (tid<32) stg(qb+B_MNR+n0+tid, mnormo[tid]);
    {
      int row=tid>>3, sub=tid&7, n=n0+row;
      float u_n=usagel[n], pr=1.f;
      for (int m=sub;m<NSLOT;m+=8){
        float um=usagel[m];
        if (um<u_n || (um==u_n && m<n)) pr*=um;
      }
      pr=red8m(pr);
      if (sub==0) stg(qb+B_ALO+n, (1.f-u_n)*pr);
    }
    if (t<NTT-1){
      int row=tid>>3, sub=tid&7;
      float wd=0.f;
      #pragma unroll
      for (int j=0;j<8;j++){ int k=sub*8+j; wd += Mem[row*MSTR+k]*wkst[k]; }
      wd=red8s(wd);
      if (sub==0) stg(qb+B_WDT+n0+row, wd);
    }

    lbar(flg, b, g, 3u+(unsigned)t, tid);
  }

  // final barrier: partials_15 published during the drain phase above
  lbar(flg, b, g, 3u+NTT, tid);
  if (g==0){
    const float* fb = ws + IFCF + ((NTT+1)&1)*PARF + b*BATF;
    float s=0.f;
    for (int gp=0;gp<GPB;gp++) s+=ldc(fb+B_RWP+gp*256+tid);
    out[(size_t)(b*NTT+(NTT-1))*256+tid]=s;
  }
}

extern "C" void kernel_launch(void* const* d_in, const int* in_sizes, int n_in,
                              void* d_out, int out_size, void* d_ws, size_t ws_size,
                              hipStream_t stream)
{
  const float* ctrl=(const float*)d_in[0];
  const float* wif =(const float*)d_in[1];
  const float* bif =(const float*)d_in[2];
  const float* mem0=(const float*)d_in[3];
  float* outp=(float*)d_out;
  unsigned* flg=(unsigned*)d_ws;
  float* wsf=(float*)((char*)d_ws+4096);

  hipMemsetAsync(d_ws, 0, 4096, stream);   // zero generation flags each launch

  void* args[]={(void*)&ctrl,(void*)&wif,(void*)&bif,(void*)&mem0,(void*)&outp,(void*)&wsf,(void*)&flg};
  hipError_t err = hipLaunchCooperativeKernel((void*)dnc_kernel, dim3(NBLK), dim3(256), args, 0, stream);
  if (err != hipSuccess){
    hipLaunchKernelGGL(dnc_kernel, dim3(NBLK), dim3(256), 0, stream,
                       ctrl, wif, bif, mem0, outp, wsf, flg);
  }
}

// Round 4
// 379.026 us; speedup vs baseline: 2.0778x; 1.4189x over previous
//
#include <hip/hip_runtime.h>
#include <math.h>

// DNC MemoryAccess forward. B=8, T=16, N=512, W=64, R=4, NW=1, MODES=3, IFACE=471.
// Persistent kernel: 128 blocks (16/batch) x 512 threads (2 waves/SIMD for latency hiding).
// L + LT + Mem shards in LDS; usage/prec/ww replicated per block. ONE relaxed flag-barrier
// per step (per-block flag in its own cache line); cross-block data via relaxed agent-scope
// atomics. wc-dots & alloc for step t+1 published during step t; read_words 2-deep pipeline.

#define NBATCH 8
#define GPB    16
#define NBLK   (NBATCH*GPB)
#define BS     512
#define NROW   32
#define NTT    16
#define NSLOT  512
#define WRD    64
#define RH     4
#define NIF    471
#define LSTR   520
#define MSTR   65
#define EPSV   1e-6f

// per-parity per-batch float offsets in exchange region
#define B_ALO  0            // [512] allocation
#define B_WDT  512          // [512] write-content raw dots
#define B_MNR  1024         // [512] memory row norms
#define B_ER   1536         // [4][512] read-content exp
#define B_SEP  3584         // [16][4] partial sums of ER
#define B_NN   3648         // [4][512] m0*bwd+m2*fwd
#define B_RWP  5696         // [16][256] read-word partials
#define BATF   9792
#define IFCF   (NBATCH*NTT*NIF)     // 60288 floats of iface
#define PARF   (NBATCH*BATF)

__device__ __forceinline__ float sigm(float x){ return 1.f/(1.f+expf(-x)); }
__device__ __forceinline__ float softpl(float x){ return x>0.f ? x+log1pf(expf(-x)) : log1pf(expf(x)); }
__device__ __forceinline__ float red16s(float v){ v+=__shfl_xor(v,1,16); v+=__shfl_xor(v,2,16); v+=__shfl_xor(v,4,16); v+=__shfl_xor(v,8,16); return v; }
__device__ __forceinline__ float red16m(float v){ v*=__shfl_xor(v,1,16); v*=__shfl_xor(v,2,16); v*=__shfl_xor(v,4,16); v*=__shfl_xor(v,8,16); return v; }
__device__ __forceinline__ float red64s(float v){
  v+=__shfl_xor(v,1); v+=__shfl_xor(v,2); v+=__shfl_xor(v,4);
  v+=__shfl_xor(v,8); v+=__shfl_xor(v,16); v+=__shfl_xor(v,32); return v; }

__device__ __forceinline__ void stg(float* p, float v){
  __hip_atomic_store(p, v, __ATOMIC_RELAXED, __HIP_MEMORY_SCOPE_AGENT);
}
__device__ __forceinline__ float ldc(const float* p){
  return __hip_atomic_load(p, __ATOMIC_RELAXED, __HIP_MEMORY_SCOPE_AGENT);
}

// flag slot: flg[b*256 + g*16] -- each block's flag in its own 64B line
__device__ __forceinline__ void lbar(unsigned* flg, int b, int g, unsigned gen, int tid){
  asm volatile("s_waitcnt vmcnt(0)" ::: "memory");
  __syncthreads();
  if (tid==0) __hip_atomic_store(flg+b*256+g*16, gen, __ATOMIC_RELAXED, __HIP_MEMORY_SCOPE_AGENT);
  if (tid<GPB){
    while (__hip_atomic_load(flg+b*256+tid*16, __ATOMIC_RELAXED, __HIP_MEMORY_SCOPE_AGENT) < gen)
      __builtin_amdgcn_s_sleep(1);
  }
  __syncthreads();
  asm volatile("" ::: "memory");
}

__global__ void __launch_bounds__(BS)
dnc_kernel(const float* __restrict__ ctrl, const float* __restrict__ wif,
           const float* __restrict__ bif, const float* __restrict__ mem0,
           float* __restrict__ out, float* __restrict__ ws, unsigned* __restrict__ flg)
{
  const int tid = threadIdx.x;
  const int bid = blockIdx.x;
  const int b   = bid & 7;
  const int g   = bid >> 3;
  const int n0  = g * NROW;

  __shared__ __align__(16) float L  [NROW*LSTR];
  __shared__ __align__(16) float LT [NROW*LSTR];
  __shared__ __align__(16) float Mem[NROW*MSTR];
  __shared__ __align__(16) float rwl[RH*NSLOT];
  __shared__ __align__(16) float wwl[NSLOT];
  __shared__ __align__(16) float usagel[NSLOT];
  __shared__ __align__(16) float precl[NSLOT];
  __shared__ __align__(16) float prs[480];
  __shared__ __align__(16) float aux[544];
  float* ern    = aux;        // [4][32]
  float* fwdb   = aux+128;    // [4][32]
  float* bwdb   = aux+256;    // [4][32]
  float* mnormo = aux+384;    // [32]
  float* modesA = aux+416;    // [12]
  float* red    = aux+432;    // [32]
  float* wkst   = aux+464;    // [64]

  // ---------------- init ----------------
  for (int i=tid; i<NROW*LSTR; i+=BS){ L[i]=0.f; LT[i]=0.f; }
  for (int i=tid; i<NROW*WRD; i+=BS){
    int r=i>>6, k=i&63;
    Mem[r*MSTR+k] = mem0[(size_t)(b*NSLOT + n0 + r)*WRD + k];
  }
  if (tid<NSLOT){ usagel[tid]=0.f; precl[tid]=0.f; }
  { // iface GEMM: this block computes iface row (b, t=g); stage ctrl row in rwl
    float* ctrlrow = rwl;
    const float* crow = ctrl + (size_t)(b*NTT+g)*1024;
    for (int i=tid;i<1024;i+=BS) ctrlrow[i]=crow[i];
    __syncthreads();
    if (tid<NIF){
      int j=tid;
      float a0=0.f,a1=0.f,a2=0.f,a3=0.f;
      const float* wp = wif + j;
      for (int c=0;c<1024;c+=4){
        a0 += ctrlrow[c+0]*wp[(size_t)(c+0)*NIF];
        a1 += ctrlrow[c+1]*wp[(size_t)(c+1)*NIF];
        a2 += ctrlrow[c+2]*wp[(size_t)(c+2)*NIF];
        a3 += ctrlrow[c+3]*wp[(size_t)(c+3)*NIF];
      }
      ws[(size_t)(b*NTT+g)*NIF + j] = ((a0+a1)+(a2+a3)) + bif[j];
    }
  }
  __syncthreads();
  for (int i=tid;i<RH*NSLOT;i+=BS) rwl[i]=0.f;

  // heavy barrier (gen 1): makes plain-stored iface visible once
  __syncthreads();
  __builtin_amdgcn_fence(__ATOMIC_RELEASE, "agent");
  if (tid==0) __hip_atomic_store(flg+b*256+g*16, 1u, __ATOMIC_RELAXED, __HIP_MEMORY_SCOPE_AGENT);
  if (tid<GPB){
    while (__hip_atomic_load(flg+b*256+tid*16, __ATOMIC_RELAXED, __HIP_MEMORY_SCOPE_AGENT) < 1u)
      __builtin_amdgcn_s_sleep(1);
  }
  __syncthreads();
  __builtin_amdgcn_fence(__ATOMIC_ACQUIRE, "agent");

  // init publish (for step 0) into parity buffer 0
  {
    float* qb = ws + IFCF + 0*PARF + b*BATF;
    if (tid<64) wkst[tid] = ws[(size_t)(b*NTT+0)*NIF + 260 + tid];
    __syncthreads();
    { // wc dots + mnorm on mem0 shard
      int row=tid>>4, sub=tid&15;
      float wd=0.f, ms=0.f;
      #pragma unroll
      for (int j=0;j<4;j++){
        int k=sub*4+j; float m=Mem[row*MSTR+k];
        wd += m*wkst[k]; ms += m*m;
      }
      wd=red16s(wd); ms=red16s(ms);
      if (sub==0){ stg(qb+B_WDT+n0+row, wd); stg(qb+B_MNR+n0+row, sqrtf(ms)); }
    }
    { // alloc_0 shard
      int row=tid>>4, sub=tid&15, n=n0+row;
      float u_n=usagel[n], pr=1.f;
      for (int m=sub;m<NSLOT;m+=16){
        float um=usagel[m];
        if (um<u_n || (um==u_n && m<n)) pr*=um;
      }
      pr=red16m(pr);
      if (sub==0) stg(qb+B_ALO+n, (1.f-u_n)*pr);
    }
  }
  lbar(flg, b, g, 2u, tid);

  // ---------------- time loop (t==NTT is the drain pseudo-step) ----------------
  for (int t=0; t<=NTT; t++){
    const float* pb = ws + IFCF + (t&1)*PARF + b*BATF;
    float*       qb = ws + IFCF + ((t+1)&1)*PARF + b*BATF;

    // ---- phase 1: assemble rw_{t-1}, read-word partials, drain out[t-2] ----
    if (t>0){
      float ev[4], nv[4];
      #pragma unroll
      for (int i=0;i<4;i++){ int idx=tid+BS*i; ev[i]=ldc(pb+B_ER+idx); nv[i]=ldc(pb+B_NN+idx); }
      if (tid<64){
        int gp=tid>>2, r=tid&3;
        float v=ldc(pb+B_SEP+gp*4+r);
        v+=__shfl_xor(v,4); v+=__shfl_xor(v,8); v+=__shfl_xor(v,16); v+=__shfl_xor(v,32);
        if (tid<4) red[tid]=v;   // Se[r]
      }
      __syncthreads();
      #pragma unroll
      for (int i=0;i<4;i++){
        int idx=tid+BS*i; int r=idx>>9;
        rwl[idx] = nv[i] + modesA[r*3+1]*ev[i]/red[r];
      }
      __syncthreads();
      if (tid<256){ // read-word partials for t-1 (Mem still = Mem_{t-1})
        int r=tid>>6, k=tid&63;
        float a=0.f;
        #pragma unroll
        for (int row=0;row<NROW;row++) a += rwl[r*NSLOT+n0+row]*Mem[row*MSTR+k];
        stg(qb+B_RWP+g*256+tid, a);
      }
      if (g==0 && t>=2 && tid<256){
        float s=0.f;
        for (int gp=0;gp<GPB;gp++) s+=ldc(pb+B_RWP+gp*256+tid);
        out[(size_t)(b*NTT+(t-2))*256+tid]=s;
      }
    }
    if (t==NTT) break;

    __syncthreads();

    // ---- phase 2a: parse iface_t ----
    {
      const float* ifc = ws + (size_t)(b*NTT+t)*NIF;
      if (tid<NIF) prs[tid]=ifc[tid];
      __syncthreads();
      if (tid<4) prs[256+tid]=softpl(prs[256+tid]);
      else if (tid==4) prs[324]=softpl(prs[324]);
      else if (tid>=64 && tid<128) prs[325+(tid-64)]=sigm(prs[325+(tid-64)]);
      else if (tid>=128 && tid<132) prs[453+(tid-128)]=sigm(prs[453+(tid-128)]);
      else if (tid==132) prs[457]=sigm(prs[457]);
      else if (tid==133) prs[458]=sigm(prs[458]);
      else if (tid>=136 && tid<140){
        int r=tid-136;
        float x0=prs[459+r*3],x1=prs[460+r*3],x2=prs[461+r*3];
        float mx=fmaxf(x0,fmaxf(x1,x2));
        float e0=expf(x0-mx),e1=expf(x1-mx),e2=expf(x2-mx),s=e0+e1+e2;
        prs[459+r*3]=e0/s; prs[460+r*3]=e1/s; prs[461+r*3]=e2/s;
        modesA[r*3+0]=e0/s; modesA[r*3+1]=e1/s; modesA[r*3+2]=e2/s;
      }
      {
        int wv=tid>>6, lane=tid&63;
        if (wv<4){
          float v = (wv==0)? prs[260+lane] : prs[(wv-1)*64+lane];
          v = red64s(v*v);
          if (lane==0) prs[471+wv]=sqrtf(v);   // 471=wk, 472..474=rk0..2
          if (wv==0){
            float u=prs[192+lane];
            u=red64s(u*u);
            if (lane==0) prs[475]=sqrtf(u);    // rk3
          }
        }
      }
      __syncthreads();
    }

    // ---- phase 2b: write-content exp, Sw, ww ----
    {
      float wsv=prs[324], wkn=prs[471];
      float wd=ldc(pb+B_WDT+tid), mn=ldc(pb+B_MNR+tid);
      float al=ldc(pb+B_ALO+tid);
      wwl[tid]=expf(wsv*wd/(wkn*mn+EPSV));
      __syncthreads();
      { float v=wwl[tid]; v=red64s(v); if ((tid&63)==0) red[4+(tid>>6)]=v; }
      __syncthreads();
      const float Sw=red[4]+red[5]+red[6]+red[7]+red[8]+red[9]+red[10]+red[11];
      float agv=prs[457], wgv=prs[458];
      wwl[tid]=wgv*(agv*al+(1.f-agv)*wwl[tid]/Sw);
    }
    __syncthreads();

    // ---- S1: Sww partials, merged L/LT update (prec old), usage update ----
    { float v=wwl[tid]; v=red64s(v); if ((tid&63)==0) red[12+(tid>>6)]=v; }
    #pragma unroll
    for (int i=0;i<8;i++){
      int e=tid+BS*i, row=e>>7, mb=(e&127)*4;
      float wn=wwl[n0+row];
      float pmn=precl[n0+row];
      float4 wm=*(float4*)&wwl[mb];
      float4 pm=*(float4*)&precl[mb];
      float c0=1.f-wn-wm.x, c1=1.f-wn-wm.y, c2=1.f-wn-wm.z, c3=1.f-wn-wm.w;
      float4 l4=*(float4*)&L[row*LSTR+mb];
      l4.x=c0*l4.x+wn*pm.x; l4.y=c1*l4.y+wn*pm.y;
      l4.z=c2*l4.z+wn*pm.z; l4.w=c3*l4.w+wn*pm.w;
      float4 t4=*(float4*)&LT[row*LSTR+mb];
      t4.x=c0*t4.x+wm.x*pmn; t4.y=c1*t4.y+wm.y*pmn;
      t4.z=c2*t4.z+wm.z*pmn; t4.w=c3*t4.w+wm.w*pmn;
      int d=(n0+row)-mb;
      if (d>=0 && d<4){ ((float*)&l4)[d]=0.f; ((float*)&t4)[d]=0.f; }
      *(float4*)&L[row*LSTR+mb]=l4;
      *(float4*)&LT[row*LSTR+mb]=t4;
    }
    {
      float wn=wwl[tid];
      float psi=(1.f-prs[453]*rwl[tid])*(1.f-prs[454]*rwl[NSLOT+tid])
               *(1.f-prs[455]*rwl[2*NSLOT+tid])*(1.f-prs[456]*rwl[3*NSLOT+tid]);
      usagel[tid]=(usagel[tid]+wn-usagel[tid]*wn)*psi;
    }
    __syncthreads();

    // ---- S2: prec update, wk_{t+1} stage, Mem update + read-content dots, fwd/bwd ----
    {
      const float Sww=red[12]+red[13]+red[14]+red[15]+red[16]+red[17]+red[18]+red[19];
      precl[tid]=(1.f-Sww)*precl[tid]+wwl[tid];
    }
    if (t<NTT-1 && tid<64) wkst[tid] = ws[(size_t)(b*NTT+t+1)*NIF + 260 + tid];
    {
      int row=tid>>4, sub=tid&15;
      float wn=wwl[n0+row];
      float rd0=0.f,rd1=0.f,rd2=0.f,rd3=0.f,ms=0.f;
      #pragma unroll
      for (int j=0;j<4;j++){
        int k=sub*4+j;
        float m=Mem[row*MSTR+k];
        m = m*(1.f-wn*prs[325+k]) + wn*prs[389+k];
        Mem[row*MSTR+k]=m;
        rd0+=prs[  0+k]*m; rd1+=prs[ 64+k]*m; rd2+=prs[128+k]*m; rd3+=prs[192+k]*m;
        ms+=m*m;
      }
      rd0=red16s(rd0); rd1=red16s(rd1); rd2=red16s(rd2); rd3=red16s(rd3); ms=red16s(ms);
      if (sub==0){
        float mn=sqrtf(ms);
        ern[0*NROW+row]=expf(prs[256]*rd0/(prs[472]*mn+EPSV));
        ern[1*NROW+row]=expf(prs[257]*rd1/(prs[473]*mn+EPSV));
        ern[2*NROW+row]=expf(prs[258]*rd2/(prs[474]*mn+EPSV));
        ern[3*NROW+row]=expf(prs[259]*rd3/(prs[475]*mn+EPSV));
        mnormo[row]=mn;
      }
    }
    { // fwd[r][n own] = L_new[n]·rw ; bwd[r][m own] = LT_new[m]·rw
      int row=tid>>4, sub=tid&15;
      const float* Lr = &L[row*LSTR];
      const float* Tr = &LT[row*LSTR];
      float fa0=0.f,fa1=0.f,fa2=0.f,fa3=0.f, ba0=0.f,ba1=0.f,ba2=0.f,ba3=0.f;
      #pragma unroll
      for (int jj=0;jj<8;jj++){
        int c4=(sub+16*jj)*4;
        float4 l4=*(const float4*)&Lr[c4];
        float4 t4=*(const float4*)&Tr[c4];
        float4 r0=*(const float4*)&rwl[0*NSLOT+c4];
        float4 r1=*(const float4*)&rwl[1*NSLOT+c4];
        float4 r2=*(const float4*)&rwl[2*NSLOT+c4];
        float4 r3=*(const float4*)&rwl[3*NSLOT+c4];
        fa0+=l4.x*r0.x+l4.y*r0.y+l4.z*r0.z+l4.w*r0.w;
        fa1+=l4.x*r1.x+l4.y*r1.y+l4.z*r1.z+l4.w*r1.w;
        fa2+=l4.x*r2.x+l4.y*r2.y+l4.z*r2.z+l4.w*r2.w;
        fa3+=l4.x*r3.x+l4.y*r3.y+l4.z*r3.z+l4.w*r3.w;
        ba0+=t4.x*r0.x+t4.y*r0.y+t4.z*r0.z+t4.w*r0.w;
        ba1+=t4.x*r1.x+t4.y*r1.y+t4.z*r1.z+t4.w*r1.w;
        ba2+=t4.x*r2.x+t4.y*r2.y+t4.z*r2.z+t4.w*r2.w;
        ba3+=t4.x*r3.x+t4.y*r3.y+t4.z*r3.z+t4.w*r3.w;
      }
      fa0=red16s(fa0); fa1=red16s(fa1); fa2=red16s(fa2); fa3=red16s(fa3);
      ba0=red16s(ba0); ba1=red16s(ba1); ba2=red16s(ba2); ba3=red16s(ba3);
      if (sub==0){
        fwdb[0*NROW+row]=fa0; fwdb[1*NROW+row]=fa1; fwdb[2*NROW+row]=fa2; fwdb[3*NROW+row]=fa3;
        bwdb[0*NROW+row]=ba0; bwdb[1*NROW+row]=ba1; bwdb[2*NROW+row]=ba2; bwdb[3*NROW+row]=ba3;
      }
    }
    __syncthreads();

    // ---- S4: publishes (NN/ER/SEP, MNR, alloc_{t+1}, wc-dots_{t+1}) ----
    if (tid<128){
      int r=tid>>5, row=tid&31;
      float e=ern[r*NROW+row];
      stg(qb+B_NN+r*NSLOT+n0+row, modesA[r*3+0]*bwdb[r*NROW+row] + modesA[r*3+2]*fwdb[r*NROW+row]);
      stg(qb+B_ER+r*NSLOT+n0+row, e);
      float v=e;
      v+=__shfl_xor(v,1,32); v+=__shfl_xor(v,2,32); v+=__shfl_xor(v,4,32);
      v+=__shfl_xor(v,8,32); v+=__shfl_xor(v,16,32);
      if (row==0) stg(qb+B_SEP+g*4+r, v);
    }
    if (tid<32) stg(qb+B_MNR+n0+tid, mnormo[tid]);
    {
      int row=tid>>4, sub=tid&15, n=n0+row;
      float u_n=usagel[n], pr=1.f;
      for (int m=sub;m<NSLOT;m+=16){
        float um=usagel[m];
        if (um<u_n || (um==u_n && m<n)) pr*=um;
      }
      pr=red16m(pr);
      if (sub==0) stg(qb+B_ALO+n, (1.f-u_n)*pr);
    }
    if (t<NTT-1){
      int row=tid>>4, sub=tid&15;
      float wd=0.f;
      #pragma unroll
      for (int j=0;j<4;j++){ int k=sub*4+j; wd += Mem[row*MSTR+k]*wkst[k]; }
      wd=red16s(wd);
      if (sub==0) stg(qb+B_WDT+n0+row, wd);
    }

    lbar(flg, b, g, 3u+(unsigned)t, tid);
  }

  // final barrier: partials_15 published during drain phase
  lbar(flg, b, g, 3u+NTT, tid);
  if (g==0 && tid<256){
    const float* fb = ws + IFCF + ((NTT+1)&1)*PARF + b*BATF;
    float s=0.f;
    for (int gp=0;gp<GPB;gp++) s+=ldc(fb+B_RWP+gp*256+tid);
    out[(size_t)(b*NTT+(NTT-1))*256+tid]=s;
  }
}

extern "C" void kernel_launch(void* const* d_in, const int* in_sizes, int n_in,
                              void* d_out, int out_size, void* d_ws, size_t ws_size,
                              hipStream_t stream)
{
  const float* ctrl=(const float*)d_in[0];
  const float* wif =(const float*)d_in[1];
  const float* bif =(const float*)d_in[2];
  const float* mem0=(const float*)d_in[3];
  float* outp=(float*)d_out;
  unsigned* flg=(unsigned*)d_ws;
  float* wsf=(float*)((char*)d_ws+8192);

  hipMemsetAsync(d_ws, 0, 8192, stream);   // zero generation flags each launch

  void* args[]={(void*)&ctrl,(void*)&wif,(void*)&bif,(void*)&mem0,(void*)&outp,(void*)&wsf,(void*)&flg};
  hipError_t err = hipLaunchCooperativeKernel((void*)dnc_kernel, dim3(NBLK), dim3(BS), args, 0, stream);
  if (err != hipSuccess){
    hipLaunchKernelGGL(dnc_kernel, dim3(NBLK), dim3(BS), 0, stream,
                       ctrl, wif, bif, mem0, outp, wsf, flg);
  }
}